// Round 1
// baseline (103413.757 us; speedup 1.0000x reference)
//
#include <hip/hip_runtime.h>
#include <math.h>

namespace {
constexpr int kB = 64;
constexpr int kT = 1024;
constexpr int kH = 512;
constexpr int kL = 3;
constexpr int kG = 2048;  // 4*H, gate order i,f,g,o

// ---- pack Whh into K-blocked float4 layout: wt4[kb][j] = Whh[j][4kb..4kb+3] ----
__global__ void prep_kernel(const float* __restrict__ whh,
                            const float* __restrict__ bih,
                            const float* __restrict__ bhh,
                            float4* __restrict__ wt4,
                            float* __restrict__ bias) {
  int idx = blockIdx.x * blockDim.x + threadIdx.x;  // (kH/4)*kG total
  int kb = idx >> 11;
  int j = idx & 2047;
  wt4[idx] = *reinterpret_cast<const float4*>(whh + (size_t)j * kH + kb * 4);
  if (idx < kG) bias[idx] = bih[idx] + bhh[idx];
}

__global__ void init_state_kernel(float* __restrict__ p) {
  p[blockIdx.x * blockDim.x + threadIdx.x] = 0.f;
}

// ---- input projection: xg[b,tl,n] = sum_k A[b,t0+tl,k]*Wih[n,k] + bias[n] ----
constexpr int BM = 64, BN = 64, BK = 16;
__global__ __launch_bounds__(256) void proj_kernel(
    const float* __restrict__ A, const float* __restrict__ W,
    const float* __restrict__ bias, float* __restrict__ xg, int t0, int Tc) {
  __shared__ __align__(16) float As[BK][BM + 4];
  __shared__ __align__(16) float Bs[BK][BN + 4];
  const int tid = threadIdx.x;
  const int n0 = blockIdx.x * BN;
  const int r0 = blockIdx.y * BM;  // row = b*Tc + tl
  const int lr = tid >> 2;         // 0..63
  const int lk = (tid & 3) << 2;   // float4 k-offset
  const int r = r0 + lr;
  const int b = r / Tc;
  const int tl = r - b * Tc;
  const float* arow = A + (size_t)(b * kT + t0 + tl) * kH;
  const float* wrow = W + (size_t)(n0 + lr) * kH;
  const int tx = tid & 15, ty = tid >> 4;
  float acc[4][4];
#pragma unroll
  for (int i = 0; i < 4; ++i)
#pragma unroll
    for (int j = 0; j < 4; ++j) acc[i][j] = 0.f;

  for (int k0 = 0; k0 < kH; k0 += BK) {
    float4 av = *reinterpret_cast<const float4*>(arow + k0 + lk);
    float4 bv = *reinterpret_cast<const float4*>(wrow + k0 + lk);
    As[lk + 0][lr] = av.x; As[lk + 1][lr] = av.y;
    As[lk + 2][lr] = av.z; As[lk + 3][lr] = av.w;
    Bs[lk + 0][lr] = bv.x; Bs[lk + 1][lr] = bv.y;
    Bs[lk + 2][lr] = bv.z; Bs[lk + 3][lr] = bv.w;
    __syncthreads();
#pragma unroll
    for (int kk = 0; kk < BK; ++kk) {
      float4 a4 = *reinterpret_cast<const float4*>(&As[kk][ty << 2]);
      float4 b4 = *reinterpret_cast<const float4*>(&Bs[kk][tx << 2]);
      float a[4] = {a4.x, a4.y, a4.z, a4.w};
      float bb[4] = {b4.x, b4.y, b4.z, b4.w};
#pragma unroll
      for (int i = 0; i < 4; ++i)
#pragma unroll
        for (int j = 0; j < 4; ++j) acc[i][j] += a[i] * bb[j];
    }
    __syncthreads();
  }
#pragma unroll
  for (int i = 0; i < 4; ++i) {
    int row = r0 + (ty << 2) + i;
    int col = n0 + (tx << 2);
    float4 o;
    o.x = acc[i][0] + bias[col + 0];
    o.y = acc[i][1] + bias[col + 1];
    o.z = acc[i][2] + bias[col + 2];
    o.w = acc[i][3] + bias[col + 3];
    *reinterpret_cast<float4*>(xg + (size_t)row * kG + col) = o;
  }
}

__device__ __forceinline__ float sigmoidf_(float x) {
  return 1.f / (1.f + expf(-x));
}

// ---- recurrence: one block per batch element, 1024 threads ----
// thread j computes gate rows j and j+1024 each step.
__global__ __launch_bounds__(1024) void recur_kernel(
    const float4* __restrict__ wt4, const float* __restrict__ xg,
    float* __restrict__ out, float* __restrict__ h_state,
    float* __restrict__ c_state, int t0, int Tc) {
  __shared__ __align__(16) float4 h4[kH / 4];
  __shared__ float c_sh[kH];
  __shared__ float gsm[kG];
  const int b = blockIdx.x;
  const int j = threadIdx.x;
  if (j < kH / 4) h4[j] = reinterpret_cast<const float4*>(h_state + b * kH)[j];
  if (j < kH) c_sh[j] = c_state[b * kH + j];
  __syncthreads();
  for (int tl = 0; tl < Tc; ++tl) {
    const float* xgrow = xg + (size_t)(b * Tc + tl) * kG;
    float acc0 = xgrow[j];
    float acc1 = xgrow[j + 1024];
#pragma unroll 4
    for (int kb = 0; kb < kH / 4; ++kb) {
      float4 hv = h4[kb];                      // LDS broadcast
      float4 w0 = wt4[(kb << 11) + j];         // coalesced 16B/lane
      float4 w1 = wt4[(kb << 11) + j + 1024];
      acc0 += w0.x * hv.x + w0.y * hv.y + w0.z * hv.z + w0.w * hv.w;
      acc1 += w1.x * hv.x + w1.y * hv.y + w1.z * hv.z + w1.w * hv.w;
    }
    gsm[j] = acc0;
    gsm[j + 1024] = acc1;
    __syncthreads();
    if (j < kH) {
      float ig = sigmoidf_(gsm[j]);
      float fg = sigmoidf_(gsm[j + 512]);
      float gg = tanhf(gsm[j + 1024]);
      float og = sigmoidf_(gsm[j + 1536]);
      float c = fg * c_sh[j] + ig * gg;
      c_sh[j] = c;
      float hn = og * tanhf(c);
      reinterpret_cast<float*>(h4)[j] = hn;
      out[(size_t)(b * kT + t0 + tl) * kH + j] = hn;
    }
    __syncthreads();
  }
  if (j < kH / 4) reinterpret_cast<float4*>(h_state + b * kH)[j] = h4[j];
  if (j < kH) c_state[b * kH + j] = c_sh[j];
}
}  // namespace

extern "C" void kernel_launch(void* const* d_in, const int* in_sizes, int n_in,
                              void* d_out, int out_size, void* d_ws,
                              size_t ws_size, hipStream_t stream) {
  const float* x = (const float*)d_in[0];
  const float* wih = (const float*)d_in[1];
  const float* whh = (const float*)d_in[2];
  const float* bih = (const float*)d_in[3];
  const float* bhh = (const float*)d_in[4];
  float* out = (float*)d_out;

  // workspace layout (floats): wt4 | bias | h_state | c_state | xg_chunk
  float* wt4f = (float*)d_ws;
  float* bias = wt4f + (size_t)(kH / 4) * kG * 4;  // 1,048,576 floats
  float* h_state = bias + kG;
  float* c_state = h_state + kB * kH;
  float* xg = c_state + kB * kH;
  size_t fixed_bytes = (size_t)(xg - wt4f) * sizeof(float);

  // largest time-chunk whose xg buffer fits the workspace (constant per call)
  int Tc = 8;
  for (int cand : {1024, 512, 256, 128, 64, 32, 16, 8}) {
    if (fixed_bytes + (size_t)kB * cand * kG * sizeof(float) <= ws_size) {
      Tc = cand;
      break;
    }
  }
  int nChunks = kT / Tc;

  for (int l = 0; l < kL; ++l) {
    prep_kernel<<<(kH / 4) * kG / 256, 256, 0, stream>>>(
        whh + (size_t)l * kG * kH, bih + (size_t)l * kG, bhh + (size_t)l * kG,
        (float4*)wt4f, bias);
    init_state_kernel<<<(2 * kB * kH) / 256, 256, 0, stream>>>(h_state);
    const float* A = (l == 0) ? x : out;  // layers 2,3 run in place on d_out
    for (int ci = 0; ci < nChunks; ++ci) {
      int t0 = ci * Tc;
      dim3 g(kG / BN, (kB * Tc) / BM);
      proj_kernel<<<g, 256, 0, stream>>>(A, wih + (size_t)l * kG * kH, bias, xg,
                                         t0, Tc);
      recur_kernel<<<kB, 1024, 0, stream>>>((const float4*)wt4f, xg, out,
                                            h_state, c_state, t0, Tc);
    }
  }
}

// Round 2
// 52999.506 us; speedup vs baseline: 1.9512x; 1.9512x over previous
//
#include <hip/hip_runtime.h>
#include <math.h>

namespace {
constexpr int kB = 64;
constexpr int kT = 1024;
constexpr int kH = 512;
constexpr int kL = 3;
constexpr int kG = 2048;  // 4*H, gate order i,f,g,o
constexpr int RB = 8;     // recurrence blocks (weights-stationary)
constexpr int JPB = kH / RB;  // 64 hidden units per block

typedef _Float16 half8 __attribute__((ext_vector_type(8)));
typedef float floatx4 __attribute__((ext_vector_type(4)));

// ---------------- prep / init kernels ----------------
__global__ void prep_bias_kernel(const float* __restrict__ bih,
                                 const float* __restrict__ bhh,
                                 float* __restrict__ bias) {
  int i = blockIdx.x * blockDim.x + threadIdx.x;
  if (i < kG) bias[i] = bih[i] + bhh[i];
}

__global__ void prep_wf16_kernel(const float* __restrict__ whh,
                                 _Float16* __restrict__ wf) {
  int i = blockIdx.x * blockDim.x + threadIdx.x;  // kG*kH total
  wf[i] = (_Float16)whh[i];
}

__global__ void zero_f32_kernel(float* __restrict__ p, int n) {
  int i = blockIdx.x * blockDim.x + threadIdx.x;
  if (i < n) p[i] = 0.f;
}

__global__ void zero_cnt_kernel(unsigned* __restrict__ c) { *c = 0u; }

// ---------------- input projection (unchanged fp32 GEMM) ----------------
constexpr int BM = 64, BN = 64, BK = 16;
__global__ __launch_bounds__(256) void proj_kernel(
    const float* __restrict__ A, const float* __restrict__ W,
    const float* __restrict__ bias, float* __restrict__ xg, int t0, int Tc) {
  __shared__ __align__(16) float As[BK][BM + 4];
  __shared__ __align__(16) float Bs[BK][BN + 4];
  const int tid = threadIdx.x;
  const int n0 = blockIdx.x * BN;
  const int r0 = blockIdx.y * BM;  // row = b*Tc + tl
  const int lr = tid >> 2;
  const int lk = (tid & 3) << 2;
  const int r = r0 + lr;
  const int b = r / Tc;
  const int tl = r - b * Tc;
  const float* arow = A + (size_t)(b * kT + t0 + tl) * kH;
  const float* wrow = W + (size_t)(n0 + lr) * kH;
  const int tx = tid & 15, ty = tid >> 4;
  float acc[4][4];
#pragma unroll
  for (int i = 0; i < 4; ++i)
#pragma unroll
    for (int j = 0; j < 4; ++j) acc[i][j] = 0.f;

  for (int k0 = 0; k0 < kH; k0 += BK) {
    float4 av = *reinterpret_cast<const float4*>(arow + k0 + lk);
    float4 bv = *reinterpret_cast<const float4*>(wrow + k0 + lk);
    As[lk + 0][lr] = av.x; As[lk + 1][lr] = av.y;
    As[lk + 2][lr] = av.z; As[lk + 3][lr] = av.w;
    Bs[lk + 0][lr] = bv.x; Bs[lk + 1][lr] = bv.y;
    Bs[lk + 2][lr] = bv.z; Bs[lk + 3][lr] = bv.w;
    __syncthreads();
#pragma unroll
    for (int kk = 0; kk < BK; ++kk) {
      float4 a4 = *reinterpret_cast<const float4*>(&As[kk][ty << 2]);
      float4 b4 = *reinterpret_cast<const float4*>(&Bs[kk][tx << 2]);
      float a[4] = {a4.x, a4.y, a4.z, a4.w};
      float bb[4] = {b4.x, b4.y, b4.z, b4.w};
#pragma unroll
      for (int i = 0; i < 4; ++i)
#pragma unroll
        for (int j = 0; j < 4; ++j) acc[i][j] += a[i] * bb[j];
    }
    __syncthreads();
  }
#pragma unroll
  for (int i = 0; i < 4; ++i) {
    int row = r0 + (ty << 2) + i;
    int col = n0 + (tx << 2);
    float4 o;
    o.x = acc[i][0] + bias[col + 0];
    o.y = acc[i][1] + bias[col + 1];
    o.z = acc[i][2] + bias[col + 2];
    o.w = acc[i][3] + bias[col + 3];
    *reinterpret_cast<float4*>(xg + (size_t)row * kG + col) = o;
  }
}

__device__ __forceinline__ float sigf(float x) {
  return 1.f / (1.f + __expf(-x));
}
__device__ __forceinline__ float tanh_fast(float x) {
  float e = __expf(2.f * x);
  return (e - 1.f) / (e + 1.f);
}

// ---------------- persistent weights-stationary recurrence ----------------
// 8 blocks x 256 threads. Block owns hidden slice [bid*64, bid*64+64) across
// all 4 gates (256 gate rows), all 64 batches. W held in VGPRs as MFMA
// B-fragments (4 gates x 16 ksteps x half8 = 256 VGPRs). H ping-pongs through
// global memory in MFMA-A-fragment-linear f16 layout; custom 8-block barrier.
__global__ __launch_bounds__(256, 1) void recur_mfma(
    const _Float16* __restrict__ wf, const float* __restrict__ xg,
    _Float16* __restrict__ hg,  // 2 * 32768 halves, frag-linear ping-pong
    float* __restrict__ out, float* __restrict__ c_state,
    unsigned* __restrict__ cnt, int t0, int Tc) {
  const int tid = threadIdx.x;
  const int w = tid >> 6;       // wave 0..3 -> jl range
  const int lane = tid & 63;
  const int l15 = lane & 15;    // MFMA col / m
  const int q = lane >> 4;      // MFMA quad
  const int bid = blockIdx.x;
  const int jl = w * 16 + l15;       // block-local hidden 0..63
  const int jg = bid * JPB + jl;     // global hidden 0..511
  __shared__ _Float16 Hsh[kB * kH];  // 64 KB, frag-linear

  // --- preload W B-fragments into registers (persistent) ---
  half8 wfrag[4][16];
#pragma unroll
  for (int g = 0; g < 4; ++g) {
    const _Float16* wr = wf + (size_t)(g * kH + jg) * kH;
#pragma unroll
    for (int ks = 0; ks < 16; ++ks)
      wfrag[g][ks] = *reinterpret_cast<const half8*>(wr + ks * 32 + q * 8);
  }
  // --- preload cell state ---
  float c[4][4];
#pragma unroll
  for (int mt = 0; mt < 4; ++mt)
#pragma unroll
    for (int rg = 0; rg < 4; ++rg) {
      int b = mt * 16 + q * 4 + rg;
      c[mt][rg] = c_state[b * kH + jg];
    }

  const int ksj = bid * 2 + (jl >> 5);  // k-region of this thread's h writes
  const int quadj = (jl >> 3) & 3;
  const int jj = jl & 7;

  for (int t = 0; t < Tc; ++t) {
    const _Float16* __restrict__ hin = hg + (size_t)(t & 1) * 32768;
    _Float16* __restrict__ hout = hg + (size_t)((t & 1) ^ 1) * 32768;

    // xg prefetch (overlaps staging + MFMA phase)
    float xv[4][4][4];
#pragma unroll
    for (int mt = 0; mt < 4; ++mt)
#pragma unroll
      for (int g = 0; g < 4; ++g)
#pragma unroll
        for (int rg = 0; rg < 4; ++rg) {
          int b = mt * 16 + q * 4 + rg;
          xv[mt][g][rg] = xg[(size_t)(b * Tc + t) * kG + g * kH + jg];
        }

    // stage H (frag-linear identity copy; wave w stages quarter w)
    {
      half8 stg[16];
#pragma unroll
      for (int it = 0; it < 16; ++it)
        stg[it] = *reinterpret_cast<const half8*>(hin + (w * 16 + it) * 512 +
                                                  lane * 8);
#pragma unroll
      for (int it = 0; it < 16; ++it)
        *reinterpret_cast<half8*>(&Hsh[(w * 16 + it) * 512 + lane * 8]) =
            stg[it];
    }
    __syncthreads();

    floatx4 zero4 = {0.f, 0.f, 0.f, 0.f};
    floatx4 acc[4][4];
#pragma unroll
    for (int mt = 0; mt < 4; ++mt)
#pragma unroll
      for (int g = 0; g < 4; ++g) acc[mt][g] = zero4;

#pragma unroll
    for (int ks = 0; ks < 16; ++ks) {
      half8 af[4];
#pragma unroll
      for (int mt = 0; mt < 4; ++mt)
        af[mt] = *reinterpret_cast<const half8*>(
            &Hsh[((mt * 16 + ks) * 64 + lane) * 8]);
#pragma unroll
      for (int mt = 0; mt < 4; ++mt)
#pragma unroll
        for (int g = 0; g < 4; ++g)
          acc[mt][g] = __builtin_amdgcn_mfma_f32_16x16x32_f16(
              af[mt], wfrag[g][ks], acc[mt][g], 0, 0, 0);
    }

    // elementwise LSTM update — all 4 gates of (b, jg) live in this lane
#pragma unroll
    for (int mt = 0; mt < 4; ++mt)
#pragma unroll
      for (int rg = 0; rg < 4; ++rg) {
        int b = mt * 16 + q * 4 + rg;
        float gi = acc[mt][0][rg] + xv[mt][0][rg];
        float gf = acc[mt][1][rg] + xv[mt][1][rg];
        float gg = acc[mt][2][rg] + xv[mt][2][rg];
        float go = acc[mt][3][rg] + xv[mt][3][rg];
        float ig = sigf(gi), fg = sigf(gf), zg = tanh_fast(gg), og = sigf(go);
        float cn = fg * c[mt][rg] + ig * zg;
        c[mt][rg] = cn;
        float h = og * tanh_fast(cn);
        out[(size_t)b * (kT * kH) + (size_t)(t0 + t) * kH + jg] = h;
        hout[(((b >> 4) * 16 + ksj) * 64 + quadj * 16 + (b & 15)) * 8 + jj] =
            (_Float16)h;
      }

    // device-scope barrier across the 8 blocks
    __threadfence();
    __syncthreads();
    if (tid == 0) {
      __hip_atomic_fetch_add(cnt, 1u, __ATOMIC_RELEASE,
                             __HIP_MEMORY_SCOPE_AGENT);
      unsigned tgt = (unsigned)(RB * (t + 1));
      while (__hip_atomic_load(cnt, __ATOMIC_ACQUIRE,
                               __HIP_MEMORY_SCOPE_AGENT) < tgt)
        __builtin_amdgcn_s_sleep(2);
    }
    __syncthreads();
  }

#pragma unroll
  for (int mt = 0; mt < 4; ++mt)
#pragma unroll
    for (int rg = 0; rg < 4; ++rg) {
      int b = mt * 16 + q * 4 + rg;
      c_state[b * kH + jg] = c[mt][rg];
    }
}
}  // namespace

extern "C" void kernel_launch(void* const* d_in, const int* in_sizes, int n_in,
                              void* d_out, int out_size, void* d_ws,
                              size_t ws_size, hipStream_t stream) {
  const float* x = (const float*)d_in[0];
  const float* wih = (const float*)d_in[1];
  const float* whh = (const float*)d_in[2];
  const float* bih = (const float*)d_in[3];
  const float* bhh = (const float*)d_in[4];
  float* out = (float*)d_out;

  // workspace layout (floats): wf16 | hg | c_state | bias | cnt | xg_chunk
  float* wsf = (float*)d_ws;
  _Float16* wf16 = (_Float16*)wsf;                     // 1M halves (2 MB)
  float* hg_f = wsf + (size_t)kG * kH / 2;             // 65536 halves (128 KB)
  float* c_state = hg_f + 32768 / 2 * 2;               // hg = 32768 floats
  // recompute cleanly:
  hg_f = wsf + 524288;
  c_state = wsf + 524288 + 32768;
  float* bias = wsf + 524288 + 32768 + 32768;
  unsigned* cnt = (unsigned*)(wsf + 524288 + 32768 + 32768 + 2048);
  float* xgbuf = wsf + 524288 + 32768 + 32768 + 2048 + 16;
  _Float16* hg = (_Float16*)hg_f;
  size_t fixed_bytes = (size_t)(xgbuf - wsf) * sizeof(float);

  // largest time-chunk whose xg buffer fits the workspace (constant per call)
  int Tc = 8;
  for (int cand : {1024, 512, 256, 128, 64, 32, 16, 8}) {
    if (fixed_bytes + (size_t)kB * cand * kG * sizeof(float) <= ws_size) {
      Tc = cand;
      break;
    }
  }
  int nChunks = kT / Tc;

  for (int l = 0; l < kL; ++l) {
    prep_bias_kernel<<<(kG + 255) / 256, 256, 0, stream>>>(
        bih + (size_t)l * kG, bhh + (size_t)l * kG, bias);
    prep_wf16_kernel<<<(kG * kH) / 256, 256, 0, stream>>>(
        whh + (size_t)l * kG * kH, wf16);
    // zero hg (both parities) + c_state = 65536 floats
    zero_f32_kernel<<<65536 / 256, 256, 0, stream>>>(hg_f, 65536);
    const float* A = (l == 0) ? x : out;  // layers 2,3 run in place on d_out
    for (int ci = 0; ci < nChunks; ++ci) {
      int t0 = ci * Tc;
      dim3 g(kG / BN, (kB * Tc) / BM);
      proj_kernel<<<g, 256, 0, stream>>>(A, wih + (size_t)l * kG * kH, bias,
                                         xgbuf, t0, Tc);
      zero_cnt_kernel<<<1, 1, 0, stream>>>(cnt);
      recur_mfma<<<RB, 256, 0, stream>>>(wf16, xgbuf, hg, out, c_state, cnt,
                                         t0, Tc);
    }
  }
}